// Round 7
// baseline (50.719 us; speedup 1.0000x reference)
//
#include <hip/hip_runtime.h>
#include <hip/hip_cooperative_groups.h>

namespace cg = cooperative_groups;

typedef float f32x4 __attribute__((ext_vector_type(4)));

#define B_ 8
#define N_ 256
#define D_ 128

// ---------------------------------------------------------------------------
// Single cooperative dispatch. 256 blocks x 512 threads = 1 block/CU.
// Block bid: b = bid&7 (XCD-affine under round-robin), slot = bid>>3,
//            rows r0 = b*N + slot*8.
// Phase 1 (R2-proven GEMM): W staged via LDS in 32-row chunks (each W elem
//   read from L2 once per block); 256 active threads = 4 waves x (2 rows,
//   f32x4 of 256 concat cols). A-half (+bias) stays in LDS As; C-half -> ws.
// grid.sync() -- runtime-managed, replaces the 2nd dispatch + drain.
// Phase 2: thread = (fq 0..31, rg 0..1 -> 4 rows, jg 0..7 -> 32 j).
//   Each C f32x4 load feeds 4 rows x 6 pk-ops; one LDS exchange.
// ---------------------------------------------------------------------------
__global__ __launch_bounds__(512, 1) void fused_coop_kernel(
    const float* __restrict__ x, const float* __restrict__ W,
    const float* __restrict__ bias, float* __restrict__ C,
    float* __restrict__ out) {

    __shared__ float  xs[8][D_];      // 4 KB
    __shared__ float4 Ws[32][64];     // 32 KB
    __shared__ f32x4  As[8][32];      // 4 KB (A tile, bias folded)
    __shared__ f32x4  part[8][8][32]; // 32 KB (phase-2 partials)

    const int tid  = threadIdx.x;
    const int bid  = blockIdx.x;
    const int b    = bid & 7;
    const int slot = bid >> 3;
    const int r0   = b * N_ + slot * 8;

    // stage x tile (8 rows x 128) -- covered by first chunk's barrier
    if (tid < 256) {
        const int row = tid >> 5, dq = tid & 31;
        reinterpret_cast<float4*>(&xs[row][0])[dq] =
            *reinterpret_cast<const float4*>(x + (size_t)(r0 + row) * D_ + dq * 4);
    }

    // ---- phase 1: GEMM ----
    const int rq    = (tid >> 6) & 3;   // 0..3 -> rows {2rq, 2rq+1}
    const int cq    = tid & 63;         // f32x4 group over 256 concat cols
    const int halfC = cq >> 5;
    const int f     = (cq * 4) & 127;

    float4 acc0 = make_float4(0.f, 0.f, 0.f, 0.f);
    float4 acc1 = make_float4(0.f, 0.f, 0.f, 0.f);

    for (int chunk = 0; chunk < 4; ++chunk) {
        __syncthreads();
        // cooperative W stage: 2048 float4 per chunk, 4 per thread (512 thr)
        #pragma unroll
        for (int k = 0; k < 4; ++k) {
            const int id = k * 512 + tid;
            const int dd = id >> 6;          // 0..31
            const int cg = id & 63;          // 0..63
            const int srow = chunk * 32 + dd + ((cg >> 5) << 7); // +128 C-half
            Ws[dd][cg] = *reinterpret_cast<const float4*>(
                W + (size_t)srow * D_ + (cg & 31) * 4);
        }
        __syncthreads();

        if (tid < 256) {
            const int dbase = chunk * 32;
            #pragma unroll
            for (int dd = 0; dd < 32; ++dd) {
                const float4 wv = Ws[dd][cq];
                const float x0 = xs[rq * 2    ][dbase + dd];
                const float x1 = xs[rq * 2 + 1][dbase + dd];
                acc0.x += x0 * wv.x; acc0.y += x0 * wv.y;
                acc0.z += x0 * wv.z; acc0.w += x0 * wv.w;
                acc1.x += x1 * wv.x; acc1.y += x1 * wv.y;
                acc1.z += x1 * wv.z; acc1.w += x1 * wv.w;
            }
        }
    }

    if (tid < 256) {
        const int row0 = r0 + rq * 2;
        if (halfC) {
            *reinterpret_cast<float4*>(C + (size_t)row0 * D_ + f)       = acc0;
            *reinterpret_cast<float4*>(C + (size_t)(row0 + 1) * D_ + f) = acc1;
        } else {
            const float4 bv = *reinterpret_cast<const float4*>(bias + f);
            acc0.x += bv.x; acc0.y += bv.y; acc0.z += bv.z; acc0.w += bv.w;
            acc1.x += bv.x; acc1.y += bv.y; acc1.z += bv.z; acc1.w += bv.w;
            As[rq * 2    ][f >> 2] = f32x4{acc0.x, acc0.y, acc0.z, acc0.w};
            As[rq * 2 + 1][f >> 2] = f32x4{acc1.x, acc1.y, acc1.z, acc1.w};
        }
    }

    // ---- grid-wide barrier: C (global) + As (LDS) now complete ----
    cg::this_grid().sync();

    // ---- phase 2: out[r0+i][f] = sum_j relu(As[i][f] + C[b,j,f]) ----
    {
        const int fq = tid & 31;
        const int rg = (tid >> 5) & 1;   // rows rg*4 .. rg*4+3
        const int jg = tid >> 6;         // 0..7 -> j slice jg*32..+31
        const f32x4 zero = {0.f, 0.f, 0.f, 0.f};

        f32x4 av[4], acc[4];
        #pragma unroll
        for (int r = 0; r < 4; ++r) {
            av[r]  = As[rg * 4 + r][fq];
            acc[r] = zero;
        }

        const f32x4* __restrict__ Cb =
            reinterpret_cast<const f32x4*>(C) +
            ((size_t)b * N_ + jg * 32) * 32 + fq;
        #pragma unroll 4
        for (int jj = 0; jj < 32; ++jj) {
            const f32x4 cv = Cb[(size_t)jj * 32];
            #pragma unroll
            for (int r = 0; r < 4; ++r) {
                f32x4 t = av[r] + cv;
                t = __builtin_elementwise_max(t, zero);
                acc[r] += t;
            }
        }

        #pragma unroll
        for (int r = 0; r < 4; ++r) part[jg][rg * 4 + r][fq] = acc[r];
    }
    __syncthreads();

    if (tid < 256) {
        const int row = tid >> 5, ff = tid & 31;
        f32x4 s = part[0][row][ff];
        #pragma unroll
        for (int k = 1; k < 8; ++k) s += part[k][row][ff];
        reinterpret_cast<f32x4*>(out)[(size_t)(r0 + row) * 32 + ff] = s;
    }
}

// ---------------------------------------------------------------------------
// Fallback two-kernel path (R6-proven), used if cooperative launch fails.
// ---------------------------------------------------------------------------
__global__ __launch_bounds__(256) void gemm_ac_kernel(
    const float* __restrict__ x, const float* __restrict__ W,
    const float* __restrict__ bias, float* __restrict__ A, float* __restrict__ C) {
    __shared__ float  xs[8][D_];
    __shared__ float4 Ws[32][64];

    const int tid  = threadIdx.x;
    const int r0   = blockIdx.x * 8;
    const int rq   = tid >> 6;
    const int cq   = tid & 63;
    const int halfC = cq >> 5;
    const int f    = (cq * 4) & 127;

    {
        const int row = tid >> 5;
        const int dq  = tid & 31;
        reinterpret_cast<float4*>(&xs[row][0])[dq] =
            *reinterpret_cast<const float4*>(x + (size_t)(r0 + row) * D_ + dq * 4);
    }

    float4 acc0 = make_float4(0.f, 0.f, 0.f, 0.f);
    float4 acc1 = make_float4(0.f, 0.f, 0.f, 0.f);

    for (int chunk = 0; chunk < 4; ++chunk) {
        if (chunk) __syncthreads();
        #pragma unroll
        for (int k = 0; k < 8; ++k) {
            const int id = k * 256 + tid;
            const int dd = id >> 6;
            const int cg = id & 63;
            const int srow = chunk * 32 + dd + ((cg >> 5) << 7);
            Ws[dd][cg] = *reinterpret_cast<const float4*>(
                W + (size_t)srow * D_ + (cg & 31) * 4);
        }
        __syncthreads();

        const int dbase = chunk * 32;
        #pragma unroll
        for (int dd = 0; dd < 32; ++dd) {
            const float4 wv = Ws[dd][cq];
            const float x0 = xs[rq * 2    ][dbase + dd];
            const float x1 = xs[rq * 2 + 1][dbase + dd];
            acc0.x += x0 * wv.x; acc0.y += x0 * wv.y;
            acc0.z += x0 * wv.z; acc0.w += x0 * wv.w;
            acc1.x += x1 * wv.x; acc1.y += x1 * wv.y;
            acc1.z += x1 * wv.z; acc1.w += x1 * wv.w;
        }
    }

    const int row0 = r0 + rq * 2;
    if (halfC) {
        *reinterpret_cast<float4*>(C + (size_t)row0 * D_ + f)       = acc0;
        *reinterpret_cast<float4*>(C + (size_t)(row0 + 1) * D_ + f) = acc1;
    } else {
        const float4 bv = *reinterpret_cast<const float4*>(bias + f);
        acc0.x += bv.x; acc0.y += bv.y; acc0.z += bv.z; acc0.w += bv.w;
        acc1.x += bv.x; acc1.y += bv.y; acc1.z += bv.z; acc1.w += bv.w;
        *reinterpret_cast<float4*>(A + (size_t)row0 * D_ + f)       = acc0;
        *reinterpret_cast<float4*>(A + (size_t)(row0 + 1) * D_ + f) = acc1;
    }
}

__global__ __launch_bounds__(256) void reduce_edges_kernel(
    const float* __restrict__ A, const float* __restrict__ C,
    float* __restrict__ out) {
    __shared__ f32x4 part[8][4][32];

    const int blk = blockIdx.x;
    const int b   = blk >> 6;
    const int i0  = (blk & 63) * 4;
    const int tid = threadIdx.x;
    const int fq  = tid & 31;
    const int jg  = tid >> 5;

    f32x4 av[4], acc[4];
    const f32x4 zero = {0.f, 0.f, 0.f, 0.f};
    #pragma unroll
    for (int r = 0; r < 4; ++r) {
        av[r] = *reinterpret_cast<const f32x4*>(
            A + ((size_t)(b * N_ + i0 + r)) * D_ + fq * 4);
        acc[r] = zero;
    }

    const f32x4* __restrict__ Cv =
        reinterpret_cast<const f32x4*>(C + (size_t)b * N_ * D_) +
        (size_t)(jg * 32) * 32 + fq;
    #pragma unroll 4
    for (int j = 0; j < 32; ++j) {
        const f32x4 cv = Cv[(size_t)j * 32];
        #pragma unroll
        for (int r = 0; r < 4; ++r) {
            f32x4 t = av[r] + cv;
            t = __builtin_elementwise_max(t, zero);
            acc[r] += t;
        }
    }

    #pragma unroll
    for (int r = 0; r < 4; ++r) part[jg][r][fq] = acc[r];
    __syncthreads();

    if (tid < 128) {
        const int rr = tid >> 5, ff = tid & 31;
        f32x4 s = part[0][rr][ff];
        #pragma unroll
        for (int k = 1; k < 8; ++k) s += part[k][rr][ff];
        *reinterpret_cast<f32x4*>(
            out + ((size_t)(b * N_ + i0 + rr)) * D_ + ff * 4) = s;
    }
}

__global__ __launch_bounds__(128) void fused_naive_kernel(
    const float* __restrict__ x, const float* __restrict__ W,
    const float* __restrict__ bias, float* __restrict__ out) {
    const int r = blockIdx.x;
    const int b = r / N_;
    const int f = threadIdx.x;
    const float* __restrict__ xi = x + (size_t)r * D_;
    float a = bias[f];
    for (int d = 0; d < D_; ++d) a += xi[d] * W[d * D_ + f];
    float acc = 0.0f;
    const float* __restrict__ xb = x + (size_t)b * N_ * D_;
    for (int j = 0; j < N_; ++j) {
        const float* __restrict__ xj = xb + (size_t)j * D_;
        float c = 0.0f;
        for (int d = 0; d < D_; ++d) c += xj[d] * W[(D_ + d) * D_ + f];
        acc += fmaxf(a + c, 0.0f);
    }
    out[(size_t)r * D_ + f] = acc;
}

extern "C" void kernel_launch(void* const* d_in, const int* in_sizes, int n_in,
                              void* d_out, int out_size, void* d_ws, size_t ws_size,
                              hipStream_t stream) {
    const float* x    = (const float*)d_in[0];   // (B, N, D) fp32
    const float* W    = (const float*)d_in[1];   // (2D, D)   fp32
    const float* bias = (const float*)d_in[2];   // (D,)      fp32
    float* out = (float*)d_out;                  // (B, N, D) fp32

    const size_t elems = (size_t)B_ * N_ * D_;

    if (ws_size >= 2 * elems * sizeof(float)) {
        float* C = (float*)d_ws;
        float* A = C + elems;   // only used by fallback path

        void* args[] = {(void*)&x, (void*)&W, (void*)&bias, (void*)&C, (void*)&out};
        hipError_t err = hipLaunchCooperativeKernel(
            (const void*)fused_coop_kernel, dim3(256), dim3(512), args, 0, stream);
        if (err != hipSuccess) {
            // fallback: proven two-kernel path
            gemm_ac_kernel<<<(B_ * N_) / 8, 256, 0, stream>>>(x, W, bias, A, C);
            reduce_edges_kernel<<<(B_ * N_) / 4, 256, 0, stream>>>(A, C, out);
        }
    } else {
        fused_naive_kernel<<<B_ * N_, D_, 0, stream>>>(x, W, bias, out);
    }
}

// Round 9
// 19.699 us; speedup vs baseline: 2.5747x; 2.5747x over previous
//
#include <hip/hip_runtime.h>

typedef float f32x4 __attribute__((ext_vector_type(4)));

#define B_ 8
#define N_ 256
#define D_ 128

// ---------------------------------------------------------------------------
// Single dispatch, zero inter-block deps. 256 blocks x 512 threads.
// Block: b = bid&7 (XCD-affine), colgroup g = bid>>3 -> 4 f-cols f0=g*4.
// Phase 1 (GEMM, no redundancy): threads 0-255 compute a[r][f0..f0+3]
//   (W rows 0..127) kept in regs (+bias); threads 256-511 compute
//   c[r][f0..f0+3] (W rows 128..255) -> LDS CS[4][256].
// Phase 2: bitonic sort each CS column ascending (36 stages, barrier each).
// Phase 3: suffix sums S0[col][i] = sum_{t>=i} CS[col][t] (Hillis-Steele).
// Phase 4: out[b,i,f] = a*K + S where K = #{c_j > -a}, S = suffix sum at the
//   first index with c > -a (8-step binary search). Exact fp32 (order only).
// ---------------------------------------------------------------------------
__global__ __launch_bounds__(512) void sorted_relational_kernel(
    const float* __restrict__ x, const float* __restrict__ W,
    const float* __restrict__ bias, float* __restrict__ out) {

    __shared__ float Wc[256][4];    // 4 KB   W[r][f0..f0+3], rows 0..255
    __shared__ float CS[4][256];    // 4 KB   c columns -> sorted ascending
    __shared__ float S0[4][257];    // 4.1 KB suffix sums (S0[c][256] = 0)
    __shared__ float S1[4][257];    // 4.1 KB scan ping-pong

    const int tid = threadIdx.x;
    const int bid = blockIdx.x;
    const int b   = bid & 7;
    const int f0  = (bid >> 3) * 4;

    // stage W columns: row t -> Wc[t][0..3]
    if (tid < 256) {
        *reinterpret_cast<f32x4*>(&Wc[tid][0]) =
            *reinterpret_cast<const f32x4*>(W + (size_t)tid * D_ + f0);
    }
    __syncthreads();

    // ---- phase 1: GEMM ----
    const int r    = tid & 255;        // row 0..255
    const int half = tid >> 8;         // 0 = a (W rows 0..127), 1 = c (128..255)
    const float* __restrict__ xr = x + ((size_t)b * N_ + r) * D_;

    f32x4 acc = {0.f, 0.f, 0.f, 0.f};
    #pragma unroll 8
    for (int d4 = 0; d4 < 32; ++d4) {
        const f32x4 xv = *reinterpret_cast<const f32x4*>(xr + d4 * 4);
        const int wb = half * 128 + d4 * 4;
        const f32x4 w0 = *reinterpret_cast<const f32x4*>(&Wc[wb + 0][0]);
        const f32x4 w1 = *reinterpret_cast<const f32x4*>(&Wc[wb + 1][0]);
        const f32x4 w2 = *reinterpret_cast<const f32x4*>(&Wc[wb + 2][0]);
        const f32x4 w3 = *reinterpret_cast<const f32x4*>(&Wc[wb + 3][0]);
        acc += xv.x * w0 + xv.y * w1 + xv.z * w2 + xv.w * w3;
    }

    if (half) {       // c-thread: publish column values for sorting
        CS[0][r] = acc[0]; CS[1][r] = acc[1];
        CS[2][r] = acc[2]; CS[3][r] = acc[3];
    } else {          // a-thread: fold bias, keep in regs across the sort
        acc += *reinterpret_cast<const f32x4*>(bias + f0);
    }
    __syncthreads();

    // ---- phase 2: bitonic sort (4 columns x 256, ascending) ----
    {
        const int col = tid >> 7;      // 0..3
        const int m   = tid & 127;     // pair slot 0..127
        for (int k = 2; k <= 256; k <<= 1) {
            for (int j = k >> 1; j > 0; j >>= 1) {
                const int i = ((m & ~(j - 1)) << 1) | (m & (j - 1));
                const int p = i | j;
                const bool asc = (i & k) == 0;
                const float vi = CS[col][i];
                const float vp = CS[col][p];
                if ((vi > vp) == asc) {
                    CS[col][i] = vp;
                    CS[col][p] = vi;
                }
                __syncthreads();
            }
        }
    }

    // ---- phase 3: suffix sums S0[c][i] = sum_{t>=i} CS[c][t] ----
    {
        const int col = tid >> 7;
        const int m   = tid & 127;
        S0[col][m]       = CS[col][m];
        S0[col][m + 128] = CS[col][m + 128];
        if (m == 0) { S0[col][256] = 0.f; S1[col][256] = 0.f; }
        __syncthreads();

        float (*src)[257] = S0;
        float (*dst)[257] = S1;
        for (int d = 1; d <= 128; d <<= 1) {
            const int i0 = m, i1 = m + 128;
            const float v0 = src[col][i0] + (i0 + d < 256 ? src[col][i0 + d] : 0.f);
            const float v1 = src[col][i1] + (i1 + d < 256 ? src[col][i1 + d] : 0.f);
            dst[col][i0] = v0;
            dst[col][i1] = v1;
            __syncthreads();
            float (*t)[257] = src; src = dst; dst = t;
        }
        // 8 stages (d=1..128): last write lands in S0
    }

    // ---- phase 4: binary search + closed form, a-threads only ----
    if (half == 0) {
        float res[4];
        #pragma unroll
        for (int c = 0; c < 4; ++c) {
            const float a  = acc[c];
            const float na = -a;
            int lo = 0, hi = 256;
            #pragma unroll
            for (int it = 0; it < 8; ++it) {
                const int mid = (lo + hi) >> 1;
                if (CS[c][mid] > na) hi = mid; else lo = mid + 1;
            }
            const float K = (float)(256 - lo);
            const float S = S0[c][lo];
            res[c] = a * K + S;
        }
        f32x4 o = {res[0], res[1], res[2], res[3]};
        *reinterpret_cast<f32x4*>(out + ((size_t)b * N_ + r) * D_ + f0) = o;
    }
}

extern "C" void kernel_launch(void* const* d_in, const int* in_sizes, int n_in,
                              void* d_out, int out_size, void* d_ws, size_t ws_size,
                              hipStream_t stream) {
    const float* x    = (const float*)d_in[0];   // (B, N, D) fp32
    const float* W    = (const float*)d_in[1];   // (2D, D)   fp32
    const float* bias = (const float*)d_in[2];   // (D,)      fp32
    float* out = (float*)d_out;                  // (B, N, D) fp32

    sorted_relational_kernel<<<B_ * (D_ / 4), 512, 0, stream>>>(x, W, bias, out);
}

// Round 10
// 19.204 us; speedup vs baseline: 2.6411x; 1.0258x over previous
//
#include <hip/hip_runtime.h>

typedef float f32x4 __attribute__((ext_vector_type(4)));

#define B_ 8
#define N_ 256
#define D_ 128

// ---------------------------------------------------------------------------
// Single dispatch, zero inter-block deps, 3 barriers. 256 blocks x 512 thr.
// Block: b = bid&7 (XCD-affine), f0 = (bid>>3)*4 -> 4 feature cols.
// Phase 1 (no redundant compute): thread (r=tid&255, half=tid>>8):
//   half=0 -> a[r][f0..3] (+bias) -> LDS AS;  half=1 -> c[r][f0..3] -> LDS CS.
//   W cols staged in LDS Wc once.
// Phase 2: thread (r, half): sum over its 128-j half of relu(AS[r]+CS[j]).
//   CS reads are wave-uniform broadcasts (all lanes same j) -> conflict-free.
//   half=1 publishes partial via LDS PR; half=0 adds and stores out.
// ---------------------------------------------------------------------------
__global__ __launch_bounds__(512) void onepass_relational_kernel(
    const float* __restrict__ x, const float* __restrict__ W,
    const float* __restrict__ bias, float* __restrict__ out) {

    __shared__ f32x4 Wc[256];   // 4 KB  W[0..255][f0..f0+3]
    __shared__ f32x4 AS[256];   // 4 KB  a + bias
    __shared__ f32x4 CS[256];   // 4 KB  c
    __shared__ f32x4 PR[256];   // 4 KB  partials from half=1

    const int tid = threadIdx.x;
    const int bid = blockIdx.x;
    const int b   = bid & 7;
    const int f0  = (bid >> 3) * 4;

    if (tid < 256) {
        Wc[tid] = *reinterpret_cast<const f32x4*>(W + (size_t)tid * D_ + f0);
    }
    __syncthreads();

    // ---- phase 1: GEMM (a and c columns, non-redundant) ----
    const int r    = tid & 255;        // row 0..255
    const int half = tid >> 8;         // 0 = a (W rows 0..127), 1 = c (128..255)
    const float* __restrict__ xr = x + ((size_t)b * N_ + r) * D_;
    const f32x4* __restrict__ Wh = &Wc[half * 128];

    f32x4 acc = {0.f, 0.f, 0.f, 0.f};
    #pragma unroll 8
    for (int d4 = 0; d4 < 32; ++d4) {
        const f32x4 xv = *reinterpret_cast<const f32x4*>(xr + d4 * 4);
        acc += xv[0] * Wh[d4 * 4 + 0] + xv[1] * Wh[d4 * 4 + 1] +
               xv[2] * Wh[d4 * 4 + 2] + xv[3] * Wh[d4 * 4 + 3];
    }

    if (half) {
        CS[r] = acc;
    } else {
        AS[r] = acc + *reinterpret_cast<const f32x4*>(bias + f0);
    }
    __syncthreads();

    // ---- phase 2: brute reduce, j split across halves ----
    const f32x4 zero = {0.f, 0.f, 0.f, 0.f};
    const f32x4 av = AS[r];
    const f32x4* __restrict__ Cj = &CS[half * 128];
    f32x4 s = zero;
    #pragma unroll 8
    for (int j = 0; j < 128; ++j) {
        s += __builtin_elementwise_max(av + Cj[j], zero);   // broadcast read
    }

    if (half) PR[r] = s;
    __syncthreads();
    if (!half) {
        s += PR[r];
        *reinterpret_cast<f32x4*>(out + ((size_t)b * N_ + r) * D_ + f0) = s;
    }
}

extern "C" void kernel_launch(void* const* d_in, const int* in_sizes, int n_in,
                              void* d_out, int out_size, void* d_ws, size_t ws_size,
                              hipStream_t stream) {
    const float* x    = (const float*)d_in[0];   // (B, N, D) fp32
    const float* W    = (const float*)d_in[1];   // (2D, D)   fp32
    const float* bias = (const float*)d_in[2];   // (D,)      fp32
    float* out = (float*)d_out;                  // (B, N, D) fp32

    onepass_relational_kernel<<<B_ * (D_ / 4), 512, 0, stream>>>(x, W, bias, out);
}